// Round 9
// baseline (136.540 us; speedup 1.0000x reference)
//
#include <hip/hip_runtime.h>

#define B      8192
#define C      2048
#define C4     (C / 4)                    // 512
#define HALF   4096
#define L      6
#define NRGB   4
#define BT     (B + L)                    // 8198
#define XOUT_ELEMS ((size_t)BT * C)       // 16789504

#define NBLK   128                        // fused blocks
#define RPB    (B / NBLK)                 // 64 rows per fused block

#define ROWF2  4099                       // float2 per adj row
#define SPANF2 2048                       // float2 per 4096-col span

typedef float v2f __attribute__((ext_vector_type(2)));   // clang vectors: nt-ops legal
typedef float v4f __attribute__((ext_vector_type(4)));

// ---------------- adj fill: one block fills cols [0, 8192) of one row ----------------
__device__ __forceinline__ void fill_row_main(const int i, const int tid,
                                              v2f* __restrict__ a2full) {
  const float ds_rgb = rsqrtf(4098.f);    // RGB sample degree = 4096+2
  const float ds_ir  = rsqrtf(4100.f);    // IR sample degree  = 4096+4
  const float dc     = rsqrtf(4097.f);    // cam-node degree   = 4096+1 (by construction)
  float v0, v1;
  if (i < HALF)          { v0 = ds_rgb * ds_rgb; v1 = 0.f; }            // RGB sample row
  else if (i < B)        { v0 = 0.f;             v1 = ds_ir * ds_ir; }  // IR sample row
  else if (i - B < NRGB) { v0 = 0.f;             v1 = dc * ds_ir; }     // RGB cam row
  else                   { v0 = dc * ds_rgb;     v1 = 0.f; }            // IR cam row
  v2f* __restrict__ a2 = a2full + (size_t)i * ROWF2;
  const v2f w0 = {v0, v0};
  const v2f w1 = {v1, v1};
  #pragma unroll
  for (int k = 0; k < 8; ++k)
    __builtin_nontemporal_store(w0, &a2[k * 256 + tid]);
  #pragma unroll
  for (int k = 0; k < 8; ++k)
    __builtin_nontemporal_store(w1, &a2[SPANF2 + k * 256 + tid]);
}

// ---------------- adj fill: one thread fills cols [8192, 8198) of one row ------------
__device__ __forceinline__ void fill_row_tail6(const int r, v2f* __restrict__ a2full) {
  const float ds_rgb = rsqrtf(4098.f);
  const float ds_ir  = rsqrtf(4100.f);
  const float dc     = rsqrtf(4097.f);
  v2f t0, t1, t2;
  if (r < HALF) {                          // RGB sample: connects to IR cams (cols 8196-97)
    const float a = ds_rgb * dc;
    t0 = (v2f){0.f, 0.f}; t1 = (v2f){0.f, 0.f}; t2 = (v2f){a, a};
  } else if (r < B) {                      // IR sample: connects to RGB cams (cols 8192-95)
    const float a = ds_ir * dc;
    t0 = (v2f){a, a}; t1 = (v2f){a, a}; t2 = (v2f){0.f, 0.f};
  } else {                                 // cam row: only diagonal
    const int l = r - B;
    const float d2 = dc * dc;
    t0 = (v2f){l == 0 ? d2 : 0.f, l == 1 ? d2 : 0.f};
    t1 = (v2f){l == 2 ? d2 : 0.f, l == 3 ? d2 : 0.f};
    t2 = (v2f){l == 4 ? d2 : 0.f, l == 5 ? d2 : 0.f};
  }
  v2f* __restrict__ a2 = a2full + (size_t)r * ROWF2 + 2 * SPANF2;
  __builtin_nontemporal_store(t0, &a2[0]);
  __builtin_nontemporal_store(t1, &a2[1]);
  __builtin_nontemporal_store(t2, &a2[2]);
}

// ---------------- Kernel 1: single-pass fused (blocks 0..NBLK-1) + adj fill (rest) --
__global__ __launch_bounds__(256) void k_main(
    const float* __restrict__ x, const int* __restrict__ cams,
    const float* __restrict__ att_w, const float* __restrict__ att_b,
    float* __restrict__ xout, float* __restrict__ partials,
    float* __restrict__ statpart, float* __restrict__ adj, const int i0) {
  const int bx  = blockIdx.x;
  const int tid = threadIdx.x;

  if (bx >= NBLK) {                       // ---- adjacency fill stream: rows [i0, BT) ----
    v2f* a2full = (v2f*)adj;
    const int nrows = BT - i0;
    const int fb = bx - NBLK;
    if (fb < nrows) {
      fill_row_main(i0 + fb, tid, a2full);
    } else {
      const int r = i0 + (fb - nrows) * 256 + tid;
      if (r < BT) fill_row_tail6(r, a2full);
    }
    return;
  }

  // ---- fused path: x read exactly once (NT), xout written NT (never re-read) ----
  __shared__ int   lcam[RPB];
  __shared__ float lbias[RPB];
  __shared__ float pl[2][4][4];           // [buf][row-in-chunk][wave]
  __shared__ float sden[L];
  __shared__ int   scnt[L];
  const int wv = tid >> 6;
  const int ln = tid & 63;
  const int r0 = bx * RPB;

  if (tid < L) { sden[tid] = 0.f; scnt[tid] = 0; }
  if (tid < RPB) {
    const int c = cams[r0 + tid];
    lcam[tid]  = c;
    lbias[tid] = att_b[c];
  }
  __syncthreads();

  const v4f* __restrict__ x4 = (const v4f*)x;
  const v4f* __restrict__ w4 = (const v4f*)att_w;
  v4f* __restrict__ o4       = (v4f*)xout;

  // preload all 6 cams' weights at this thread's two column slots (12 v4f)
  const v4f wA0 = w4[0 * C4 + tid], wC0 = w4[0 * C4 + 256 + tid];
  const v4f wA1 = w4[1 * C4 + tid], wC1 = w4[1 * C4 + 256 + tid];
  const v4f wA2 = w4[2 * C4 + tid], wC2 = w4[2 * C4 + 256 + tid];
  const v4f wA3 = w4[3 * C4 + tid], wC3 = w4[3 * C4 + 256 + tid];
  const v4f wA4 = w4[4 * C4 + tid], wC4 = w4[4 * C4 + 256 + tid];
  const v4f wA5 = w4[5 * C4 + tid], wC5 = w4[5 * C4 + 256 + tid];

  v4f a[L][2];
  #pragma unroll
  for (int l = 0; l < L; ++l) {
    a[l][0] = (v4f){0.f, 0.f, 0.f, 0.f};
    a[l][1] = (v4f){0.f, 0.f, 0.f, 0.f};
  }

  for (int cc = 0; cc < RPB / 4; ++cc) {  // 16 chunks of 4 rows
    v4f   xa[4], xc[4];
    float p[4];
    int   cm[4];
    #pragma unroll
    for (int q = 0; q < 4; ++q) {
      const int rl = cc * 4 + q;
      cm[q] = lcam[rl];
      const size_t xb = (size_t)(r0 + rl) * C4;
      xa[q] = __builtin_nontemporal_load(&x4[xb + tid]);
      xc[q] = __builtin_nontemporal_load(&x4[xb + 256 + tid]);
      __builtin_nontemporal_store(xa[q], &o4[xb + tid]);
      __builtin_nontemporal_store(xc[q], &o4[xb + 256 + tid]);
      v4f wa, wc;
      const int c = cm[q];                 // wave-uniform branch
      if      (c == 0) { wa = wA0; wc = wC0; }
      else if (c == 1) { wa = wA1; wc = wC1; }
      else if (c == 2) { wa = wA2; wc = wC2; }
      else if (c == 3) { wa = wA3; wc = wC3; }
      else if (c == 4) { wa = wA4; wc = wC4; }
      else             { wa = wA5; wc = wC5; }
      const v4f m = xa[q] * wa + xc[q] * wc;
      p[q] = m.x + m.y + m.z + m.w;
    }
    #pragma unroll
    for (int q = 0; q < 4; ++q) {
      float v = p[q];
      #pragma unroll
      for (int off = 32; off > 0; off >>= 1) v += __shfl_xor(v, off, 64);
      if (ln == 0) pl[cc & 1][q][wv] = v;
    }
    __syncthreads();
    float s[4];
    #pragma unroll
    for (int q = 0; q < 4; ++q)
      s[q] = pl[cc & 1][q][0] + pl[cc & 1][q][1] + pl[cc & 1][q][2] + pl[cc & 1][q][3]
           + lbias[cc * 4 + q];
    if (tid == 0) {
      #pragma unroll
      for (int q = 0; q < 4; ++q) {
        atomicAdd(&sden[cm[q]], s[q]);
        atomicAdd(&scnt[cm[q]], 1);
      }
    }
    #pragma unroll
    for (int q = 0; q < 4; ++q) {
      const float sq = s[q];
      const v4f va = xa[q] * sq;
      const v4f vc = xc[q] * sq;
      #define ACC(l) { a[l][0] += va; a[l][1] += vc; }
      const int c = cm[q];
      if      (c == 0) ACC(0)
      else if (c == 1) ACC(1)
      else if (c == 2) ACC(2)
      else if (c == 3) ACC(3)
      else if (c == 4) ACC(4)
      else             ACC(5)
      #undef ACC
    }
  }

  v4f* __restrict__ p4 = (v4f*)partials + (size_t)bx * (L * C4);
  #pragma unroll
  for (int l = 0; l < L; ++l) {
    p4[l * C4 + tid]       = a[l][0];
    p4[l * C4 + 256 + tid] = a[l][1];
  }
  __syncthreads();
  if (tid < L)           statpart[bx * 12 + tid] = sden[tid];
  else if (tid < 2 * L)  statpart[bx * 12 + tid] = (float)scnt[tid - L];
}

// ---------------- Kernel 2: reduce partials + stats -> tail rows of x_out ----------
__global__ __launch_bounds__(256) void k_tail(
    const float* __restrict__ partials, const float* __restrict__ statpart,
    const float* __restrict__ running_mean, float* __restrict__ xout) {
  const int l    = blockIdx.x / 32;                  // [0, 6)
  const int cg   = blockIdx.x % 32;
  const int tid  = threadIdx.x;
  const int wv   = tid >> 6;
  const int ln   = tid & 63;

  float d = 0.f, n = 0.f;
  if (tid < NBLK) {
    d = statpart[tid * 12 + l];
    n = statpart[tid * 12 + 6 + l];
  }
  #pragma unroll
  for (int off = 32; off > 0; off >>= 1) {
    d += __shfl_xor(d, off, 64);
    n += __shfl_xor(n, off, 64);
  }
  __shared__ float sdn[8];
  if (ln == 0) { sdn[wv] = d; sdn[4 + wv] = n; }

  const int c4i  = tid & 15;
  const int gs   = tid >> 4;                         // [0, 16)
  const int col4 = cg * 16 + c4i;                    // [0, 512)
  const float4* __restrict__ p4 = (const float4*)partials;
  float4 acc = make_float4(0.f, 0.f, 0.f, 0.f);
  for (int t = 0; t < NBLK / 16; ++t) {              // 8 groups per thread
    const int g = gs + t * 16;
    const float4 v = p4[((size_t)g * L + l) * C4 + col4];
    acc.x += v.x; acc.y += v.y; acc.z += v.z; acc.w += v.w;
  }
  __shared__ float4 red[16][16];
  red[gs][c4i] = acc;
  __syncthreads();
  if (tid < 16) {
    const float denom = sdn[0] + sdn[1] + sdn[2] + sdn[3];
    const float count = sdn[4] + sdn[5] + sdn[6] + sdn[7];
    const int myc4 = cg * 16 + tid;
    float4 t = make_float4(0.f, 0.f, 0.f, 0.f);
    #pragma unroll
    for (int g = 0; g < 16; ++g) {
      const float4 v = red[g][tid];
      t.x += v.x; t.y += v.y; t.z += v.z; t.w += v.w;
    }
    float4 o;
    if (count > 0.f) {
      const float inv = 1.0f / denom;
      o.x = t.x * inv; o.y = t.y * inv; o.z = t.z * inv; o.w = t.w * inv;
    } else {
      o = ((const float4*)running_mean)[(size_t)l * C4 + myc4];
    }
    ((float4*)xout)[((size_t)B + l) * C4 + myc4] = o;
  }
}

// ---------------- Kernel 3 (fallback only): fill adj rows [0, i0) -------------------
__global__ __launch_bounds__(256) void k_fill_head(float* __restrict__ adj, const int i0) {
  const int bx  = blockIdx.x;
  const int tid = threadIdx.x;
  v2f* a2full = (v2f*)adj;
  if (bx < i0) {
    fill_row_main(bx, tid, a2full);
  } else {
    const int r = (bx - i0) * 256 + tid;
    if (r < i0) fill_row_tail6(r, a2full);
  }
}

extern "C" void kernel_launch(void* const* d_in, const int* in_sizes, int n_in,
                              void* d_out, int out_size, void* d_ws, size_t ws_size,
                              hipStream_t stream) {
  const float* x            = (const float*)d_in[0];
  const int*   cams         = (const int*)d_in[1];
  const float* att_w        = (const float*)d_in[4];
  const float* att_b        = (const float*)d_in[5];
  const float* running_mean = (const float*)d_in[6];

  float* xout = (float*)d_out;
  float* adj  = xout + XOUT_ELEMS;

  const size_t PART_FLOATS = (size_t)NBLK * L * C;        // 1,572,864
  const size_t NEED_BYTES  = (PART_FLOATS + NBLK * 12) * sizeof(float);  // ~6.3 MB

  if (ws_size >= NEED_BYTES) {
    // primary: scratch in d_ws; K1 fills the ENTIRE adj. 2 dispatches.
    float* partials = (float*)d_ws;
    float* statpart = partials + PART_FLOATS;
    const int grid = NBLK + BT + (BT + 255) / 256;        // 128 + 8198 + 33
    k_main<<<grid, 256, 0, stream>>>(x, cams, att_w, att_b, xout,
                                     partials, statpart, adj, 0);
    k_tail<<<32 * L, 256, 0, stream>>>(partials, statpart, running_mean, xout);
  } else {
    // fallback: scratch in adj rows [0, i0); K1 fills rows [i0, BT);
    // K3 overwrites the scratch region last (stream-ordered).
    const int i0 = 200;                                   // 200*8198 floats >= scratch
    float* partials = adj;
    float* statpart = adj + PART_FLOATS;
    const int nrows = BT - i0;
    const int grid  = NBLK + nrows + (nrows + 255) / 256;
    k_main<<<grid, 256, 0, stream>>>(x, cams, att_w, att_b, xout,
                                     partials, statpart, adj, i0);
    k_tail     <<<32 * L, 256, 0, stream>>>(partials, statpart, running_mean, xout);
    k_fill_head<<<i0 + (i0 + 255) / 256, 256, 0, stream>>>(adj, i0);
  }
}

// Round 10
// 71.695 us; speedup vs baseline: 1.9045x; 1.9045x over previous
//
#include <hip/hip_runtime.h>

#define B      8192
#define C      2048
#define C4     (C / 4)                    // 512
#define HALF   4096
#define L      6
#define NRGB   4
#define BT     (B + L)                    // 8198
#define XOUT_ELEMS ((size_t)BT * C)       // 16789504

#define NBLK   256                        // fused blocks
#define RPB    32                        // rows per fused block (8192/256)

#define ROWF2  4099                       // float2 per adj row
#define SPANF2 2048                       // float2 per 4096-col span

typedef float v2f __attribute__((ext_vector_type(2)));   // clang vector: nt-store legal

// ---------------- adj fill: one block fills cols [0, 8192) of one row ----------------
__device__ __forceinline__ void fill_row_main(const int i, const int tid,
                                              v2f* __restrict__ a2full) {
  const float ds_rgb = rsqrtf(4098.f);    // RGB sample degree = 4096+2
  const float ds_ir  = rsqrtf(4100.f);    // IR sample degree  = 4096+4
  const float dc     = rsqrtf(4097.f);    // cam-node degree   = 4096+1 (by construction)
  float v0, v1;
  if (i < HALF)          { v0 = ds_rgb * ds_rgb; v1 = 0.f; }            // RGB sample row
  else if (i < B)        { v0 = 0.f;             v1 = ds_ir * ds_ir; }  // IR sample row
  else if (i - B < NRGB) { v0 = 0.f;             v1 = dc * ds_ir; }     // RGB cam row
  else                   { v0 = dc * ds_rgb;     v1 = 0.f; }            // IR cam row
  v2f* __restrict__ a2 = a2full + (size_t)i * ROWF2;
  const v2f w0 = {v0, v0};
  const v2f w1 = {v1, v1};
  #pragma unroll
  for (int k = 0; k < 8; ++k)
    __builtin_nontemporal_store(w0, &a2[k * 256 + tid]);
  #pragma unroll
  for (int k = 0; k < 8; ++k)
    __builtin_nontemporal_store(w1, &a2[SPANF2 + k * 256 + tid]);
}

// ---------------- adj fill: one thread fills cols [8192, 8198) of one row ------------
__device__ __forceinline__ void fill_row_tail6(const int r, v2f* __restrict__ a2full) {
  const float ds_rgb = rsqrtf(4098.f);
  const float ds_ir  = rsqrtf(4100.f);
  const float dc     = rsqrtf(4097.f);
  v2f t0, t1, t2;
  if (r < HALF) {                          // RGB sample: connects to IR cams (cols 8196-97)
    const float a = ds_rgb * dc;
    t0 = (v2f){0.f, 0.f}; t1 = (v2f){0.f, 0.f}; t2 = (v2f){a, a};
  } else if (r < B) {                      // IR sample: connects to RGB cams (cols 8192-95)
    const float a = ds_ir * dc;
    t0 = (v2f){a, a}; t1 = (v2f){a, a}; t2 = (v2f){0.f, 0.f};
  } else {                                 // cam row: only diagonal
    const int l = r - B;
    const float d2 = dc * dc;
    t0 = (v2f){l == 0 ? d2 : 0.f, l == 1 ? d2 : 0.f};
    t1 = (v2f){l == 2 ? d2 : 0.f, l == 3 ? d2 : 0.f};
    t2 = (v2f){l == 4 ? d2 : 0.f, l == 5 ? d2 : 0.f};
  }
  v2f* __restrict__ a2 = a2full + (size_t)r * ROWF2 + 2 * SPANF2;
  __builtin_nontemporal_store(t0, &a2[0]);
  __builtin_nontemporal_store(t1, &a2[1]);
  __builtin_nontemporal_store(t2, &a2[2]);
}

// ---------------- Kernel 1: single-pass fused (blocks 0..NBLK-1) + adj fill (rest) --
__global__ __launch_bounds__(256) void k_main(
    const float* __restrict__ x, const int* __restrict__ cams,
    const float* __restrict__ att_w, const float* __restrict__ att_b,
    float* __restrict__ xout, float* __restrict__ partials,
    float* __restrict__ statpart, float* __restrict__ adj, const int i0) {
  const int bx  = blockIdx.x;
  const int tid = threadIdx.x;

  if (bx >= NBLK) {                       // ---- adjacency fill stream: rows [i0, BT) ----
    v2f* a2full = (v2f*)adj;
    const int nrows = BT - i0;
    const int fb = bx - NBLK;
    if (fb < nrows) {
      fill_row_main(i0 + fb, tid, a2full);
    } else {
      const int r = i0 + (fb - nrows) * 256 + tid;
      if (r < BT) fill_row_tail6(r, a2full);
    }
    return;
  }

  // ---- fused path: x read exactly once; prioritized over store-only fill waves ----
  __builtin_amdgcn_s_setprio(1);
  __shared__ int   lcam[RPB];
  __shared__ float lbias[RPB];
  __shared__ float pl[2][4][4];           // [buf][row-in-chunk][wave]
  __shared__ float sden[L];
  __shared__ int   scnt[L];
  const int wv = tid >> 6;
  const int ln = tid & 63;
  const int r0 = bx * RPB;

  if (tid < L) { sden[tid] = 0.f; scnt[tid] = 0; }
  if (tid < RPB) {
    const int c = cams[r0 + tid];
    lcam[tid]  = c;
    lbias[tid] = att_b[c];
  }
  __syncthreads();

  const float4* __restrict__ x4 = (const float4*)x;
  const float4* __restrict__ w4 = (const float4*)att_w;
  float4* __restrict__ o4       = (float4*)xout;

  // preload all 6 cams' weights at this thread's two column slots (12 float4)
  const float4 wA0 = w4[0 * C4 + tid], wC0 = w4[0 * C4 + 256 + tid];
  const float4 wA1 = w4[1 * C4 + tid], wC1 = w4[1 * C4 + 256 + tid];
  const float4 wA2 = w4[2 * C4 + tid], wC2 = w4[2 * C4 + 256 + tid];
  const float4 wA3 = w4[3 * C4 + tid], wC3 = w4[3 * C4 + 256 + tid];
  const float4 wA4 = w4[4 * C4 + tid], wC4 = w4[4 * C4 + 256 + tid];
  const float4 wA5 = w4[5 * C4 + tid], wC5 = w4[5 * C4 + 256 + tid];

  float4 a[L][2];
  #pragma unroll
  for (int l = 0; l < L; ++l) {
    a[l][0] = make_float4(0.f, 0.f, 0.f, 0.f);
    a[l][1] = make_float4(0.f, 0.f, 0.f, 0.f);
  }

  for (int cc = 0; cc < RPB / 4; ++cc) {  // 8 chunks of 4 rows
    float4 xa[4], xc[4];
    float  p[4];
    int    cm[4];
    #pragma unroll
    for (int q = 0; q < 4; ++q) {
      const int rl = cc * 4 + q;
      cm[q] = lcam[rl];
      const size_t xb = (size_t)(r0 + rl) * C4;
      xa[q] = x4[xb + tid];
      xc[q] = x4[xb + 256 + tid];
      o4[xb + tid]       = xa[q];
      o4[xb + 256 + tid] = xc[q];
      float4 wa, wc;
      const int c = cm[q];                 // wave-uniform branch
      if      (c == 0) { wa = wA0; wc = wC0; }
      else if (c == 1) { wa = wA1; wc = wC1; }
      else if (c == 2) { wa = wA2; wc = wC2; }
      else if (c == 3) { wa = wA3; wc = wC3; }
      else if (c == 4) { wa = wA4; wc = wC4; }
      else             { wa = wA5; wc = wC5; }
      p[q] = xa[q].x * wa.x + xa[q].y * wa.y + xa[q].z * wa.z + xa[q].w * wa.w
           + xc[q].x * wc.x + xc[q].y * wc.y + xc[q].z * wc.z + xc[q].w * wc.w;
    }
    #pragma unroll
    for (int q = 0; q < 4; ++q) {
      float v = p[q];
      #pragma unroll
      for (int off = 32; off > 0; off >>= 1) v += __shfl_xor(v, off, 64);
      if (ln == 0) pl[cc & 1][q][wv] = v;
    }
    __syncthreads();
    float s[4];
    #pragma unroll
    for (int q = 0; q < 4; ++q)
      s[q] = pl[cc & 1][q][0] + pl[cc & 1][q][1] + pl[cc & 1][q][2] + pl[cc & 1][q][3]
           + lbias[cc * 4 + q];
    if (tid == 0) {
      #pragma unroll
      for (int q = 0; q < 4; ++q) {
        atomicAdd(&sden[cm[q]], s[q]);
        atomicAdd(&scnt[cm[q]], 1);
      }
    }
    #pragma unroll
    for (int q = 0; q < 4; ++q) {
      const float sq = s[q];
      float4 va, vc;
      va.x = xa[q].x * sq; va.y = xa[q].y * sq; va.z = xa[q].z * sq; va.w = xa[q].w * sq;
      vc.x = xc[q].x * sq; vc.y = xc[q].y * sq; vc.z = xc[q].z * sq; vc.w = xc[q].w * sq;
      #define ACC(l) { a[l][0].x+=va.x; a[l][0].y+=va.y; a[l][0].z+=va.z; a[l][0].w+=va.w; \
                       a[l][1].x+=vc.x; a[l][1].y+=vc.y; a[l][1].z+=vc.z; a[l][1].w+=vc.w; }
      const int c = cm[q];
      if      (c == 0) ACC(0)
      else if (c == 1) ACC(1)
      else if (c == 2) ACC(2)
      else if (c == 3) ACC(3)
      else if (c == 4) ACC(4)
      else             ACC(5)
      #undef ACC
    }
  }

  float4* __restrict__ p4 = (float4*)partials + (size_t)bx * (L * C4);
  #pragma unroll
  for (int l = 0; l < L; ++l) {
    p4[l * C4 + tid]       = a[l][0];
    p4[l * C4 + 256 + tid] = a[l][1];
  }
  __syncthreads();
  if (tid < L)           statpart[bx * 12 + tid] = sden[tid];
  else if (tid < 2 * L)  statpart[bx * 12 + tid] = (float)scnt[tid - L];
}

// ---------------- Kernel 2: reduce partials + stats -> tail rows of x_out ----------
__global__ __launch_bounds__(256) void k_tail(
    const float* __restrict__ partials, const float* __restrict__ statpart,
    const float* __restrict__ running_mean, float* __restrict__ xout) {
  const int l    = blockIdx.x / 32;                  // [0, 6)
  const int cg   = blockIdx.x % 32;
  const int tid  = threadIdx.x;
  const int wv   = tid >> 6;
  const int ln   = tid & 63;

  float d = statpart[tid * 12 + l];
  float n = statpart[tid * 12 + 6 + l];
  #pragma unroll
  for (int off = 32; off > 0; off >>= 1) {
    d += __shfl_xor(d, off, 64);
    n += __shfl_xor(n, off, 64);
  }
  __shared__ float sdn[8];
  if (ln == 0) { sdn[wv] = d; sdn[4 + wv] = n; }

  const int c4i  = tid & 15;
  const int gs   = tid >> 4;                         // [0, 16)
  const int col4 = cg * 16 + c4i;                    // [0, 512)
  const float4* __restrict__ p4 = (const float4*)partials;
  float4 acc = make_float4(0.f, 0.f, 0.f, 0.f);
  for (int t = 0; t < NBLK / 16; ++t) {
    const int g = gs + t * 16;
    const float4 v = p4[((size_t)g * L + l) * C4 + col4];
    acc.x += v.x; acc.y += v.y; acc.z += v.z; acc.w += v.w;
  }
  __shared__ float4 red[16][16];
  red[gs][c4i] = acc;
  __syncthreads();
  if (tid < 16) {
    const float denom = sdn[0] + sdn[1] + sdn[2] + sdn[3];
    const float count = sdn[4] + sdn[5] + sdn[6] + sdn[7];
    const int myc4 = cg * 16 + tid;
    float4 t = make_float4(0.f, 0.f, 0.f, 0.f);
    #pragma unroll
    for (int g = 0; g < 16; ++g) {
      const float4 v = red[g][tid];
      t.x += v.x; t.y += v.y; t.z += v.z; t.w += v.w;
    }
    float4 o;
    if (count > 0.f) {
      const float inv = 1.0f / denom;
      o.x = t.x * inv; o.y = t.y * inv; o.z = t.z * inv; o.w = t.w * inv;
    } else {
      o = ((const float4*)running_mean)[(size_t)l * C4 + myc4];
    }
    ((float4*)xout)[((size_t)B + l) * C4 + myc4] = o;
  }
}

// ---------------- Kernel 3 (fallback only): fill adj rows [0, i0) -------------------
__global__ __launch_bounds__(256) void k_fill_head(float* __restrict__ adj, const int i0) {
  const int bx  = blockIdx.x;
  const int tid = threadIdx.x;
  v2f* a2full = (v2f*)adj;
  if (bx < i0) {
    fill_row_main(bx, tid, a2full);
  } else {
    const int r = (bx - i0) * 256 + tid;
    if (r < i0) fill_row_tail6(r, a2full);
  }
}

extern "C" void kernel_launch(void* const* d_in, const int* in_sizes, int n_in,
                              void* d_out, int out_size, void* d_ws, size_t ws_size,
                              hipStream_t stream) {
  const float* x            = (const float*)d_in[0];
  const int*   cams         = (const int*)d_in[1];
  const float* att_w        = (const float*)d_in[4];
  const float* att_b        = (const float*)d_in[5];
  const float* running_mean = (const float*)d_in[6];

  float* xout = (float*)d_out;
  float* adj  = xout + XOUT_ELEMS;

  const size_t PART_FLOATS = (size_t)NBLK * L * C;        // 3,145,728
  const size_t NEED_BYTES  = (PART_FLOATS + NBLK * 12) * sizeof(float);  // ~12.6 MB

  if (ws_size >= NEED_BYTES) {
    // primary: scratch in d_ws; K1 fills the ENTIRE adj. 2 dispatches.
    float* partials = (float*)d_ws;
    float* statpart = partials + PART_FLOATS;
    const int grid = NBLK + BT + (BT + 255) / 256;        // 256 + 8198 + 33
    k_main<<<grid, 256, 0, stream>>>(x, cams, att_w, att_b, xout,
                                     partials, statpart, adj, 0);
    k_tail<<<32 * L, 256, 0, stream>>>(partials, statpart, running_mean, xout);
  } else {
    // fallback: scratch in adj rows [0, i0); K1 fills rows [i0, BT);
    // K3 overwrites the scratch region last (stream-ordered).
    const int i0 = 400;                                   // 400*8198 floats >= scratch
    float* partials = adj;
    float* statpart = adj + PART_FLOATS;
    const int nrows = BT - i0;
    const int grid  = NBLK + nrows + (nrows + 255) / 256;
    k_main<<<grid, 256, 0, stream>>>(x, cams, att_w, att_b, xout,
                                     partials, statpart, adj, i0);
    k_tail     <<<32 * L, 256, 0, stream>>>(partials, statpart, running_mean, xout);
    k_fill_head<<<i0 + (i0 + 255) / 256, 256, 0, stream>>>(adj, i0);
  }
}